// Round 9
// baseline (511.052 us; speedup 1.0000x reference)
//
#include <hip/hip_runtime.h>

// LSTM_61203283968689 — R9: MFMA fused 3-layer LSTM, BARRIER-FREE dataflow sync.
// 256 blocks x 768 threads (12 waves, 3/SIMD): waves 0-3 L0, 4-7 L1, 8-11 L2.
// R8 post-mortem: per-tick __syncthreads phase-locks all waves -> MFMA burst and
// ew-VALU burst serialize (tick = 745+721+stall). R9 removes the barrier: each
// wave publishes per-timestep progress in LDS (PROG[12]); consumers spin on
// group-min. Deps: L0(t): minL0>=t (h0(t-1)), minL1>=t-3 (h0 ring bp).
//       L1(t): minL0>=t+1 (h0(t)), minL1>=t (h1(t-1)), minL2>=t-3 (h1 ring bp).
//       L2(t): minL1>=t+1 (h1(t)), minL2>=t (h2(t-1)).
// Waves drift 1-4 steps -> one wave's MFMA burst overlaps another's trans burst
// (tick -> max(pipes), not sum). h rings: 4 slots/layer, slot = t&3.
// Wave wg owns gates {i,f,g,o} of units [16wg,16wg+16); 4 samples on C-rows
// {0,4,8,12}. Fragment-linear LDS; lane reads at lane*16B (conflict-free).
// Math identical to R6 (same MFMA order, same ew) -> absmax must stay 9.766e-4.

#define TT   512
#define NTH  768
#define NBLK 256

typedef _Float16 h16;
typedef __attribute__((ext_vector_type(8))) _Float16 h16x8;
typedef __attribute__((ext_vector_type(4))) float f32x4;

#define MFMA16(a, b, c) __builtin_amdgcn_mfma_f32_16x16x32_f16((a), (b), (c), 0, 0, 0)

__device__ __forceinline__ float sigm(float z) {
    return __builtin_amdgcn_rcpf(1.f + __expf(-z));
}

// B-fragment: 8 consecutive k of row `ro` from row-major W[.,ld], f32 -> f16.
__device__ __forceinline__ h16x8 loadB(const float* __restrict__ W, int ld, int ro,
                                       int k0, int kmax) {
    h16x8 r;
    #pragma unroll
    for (int i = 0; i < 8; ++i) {
        const int k = k0 + i;
        r[i] = (h16)((k < kmax) ? W[(size_t)ro * ld + k] : 0.f);
    }
    return r;
}

__global__ __attribute__((amdgpu_flat_work_group_size(NTH, NTH), amdgpu_waves_per_eu(3)))
void lstm_mfma(
    const float* __restrict__ x,
    const float* __restrict__ wih0, const float* __restrict__ whh0,
    const float* __restrict__ bih0, const float* __restrict__ bhh0,
    const float* __restrict__ wih1, const float* __restrict__ whh1,
    const float* __restrict__ bih1, const float* __restrict__ bhh1,
    const float* __restrict__ wih2, const float* __restrict__ whh2,
    const float* __restrict__ bih2, const float* __restrict__ bhh2,
    const float* __restrict__ wfc, const float* __restrict__ bfc,
    float* __restrict__ out)
{
    const int tid  = threadIdx.x;
    const int w    = tid >> 6;        // wave 0..11
    const int wl   = w >> 2;          // layer 0..2
    const int wg   = w & 3;           // gate-tile group: units [16wg, 16wg+16)
    const int lane = tid & 63;
    const int nloc = lane & 15;       // unit-local index / B-frag col
    const int kg   = lane >> 4;       // k-group 0..3 ; also sample (C-row 4*kg)
    const int b4   = blockIdx.x * 4;
    const int u    = wg * 16 + nloc;  // this lane's hidden unit

    // LDS: XL 64 KiB + HT 24 KiB + PROG = ~88 KiB -> 1 block/CU
    __shared__ alignas(16) h16 XL[2 * 32 * 512];   // x: 2 chunk-bufs x 32 t x frag(512)
    __shared__ alignas(16) h16 HT[3 * 4 * 1024];   // h[layer][slot=t&3] frag-tiles
    __shared__ unsigned PROG[12];                  // per-wave completed-time counters

    // ---------------- B fragments for THIS wave's layer (R6 layout) -------------
    h16x8 Bf[4][4];
    float bias[4];
    #pragma unroll
    for (int g = 0; g < 4; ++g) {
        const int ro = g * 64 + u;                  // original row (i,f,g,o blocks)
        if (wl == 0) {
            Bf[g][0] = loadB(wih0, 22, ro, kg * 8,      22);
            Bf[g][1] = loadB(whh0, 64, ro, kg * 8,      64);
            Bf[g][2] = loadB(whh0, 64, ro, 32 + kg * 8, 64);
            Bf[g][3] = Bf[g][2];                        // unused
            bias[g]  = bih0[ro] + bhh0[ro];
        } else if (wl == 1) {
            Bf[g][0] = loadB(wih1, 64, ro, kg * 8,      64);
            Bf[g][1] = loadB(wih1, 64, ro, 32 + kg * 8, 64);
            Bf[g][2] = loadB(whh1, 64, ro, kg * 8,      64);
            Bf[g][3] = loadB(whh1, 64, ro, 32 + kg * 8, 64);
            bias[g]  = bih1[ro] + bhh1[ro];
        } else {
            Bf[g][0] = loadB(wih2, 64, ro, kg * 8,      64);
            Bf[g][1] = loadB(wih2, 64, ro, 32 + kg * 8, 64);
            Bf[g][2] = loadB(whh2, 64, ro, kg * 8,      64);
            Bf[g][3] = loadB(whh2, 64, ro, 32 + kg * 8, 64);
            bias[g]  = bih2[ro] + bhh2[ro];
        }
    }
    f32x4 bz[4];
    #pragma unroll
    for (int g = 0; g < 4; ++g) { bz[g][0] = bias[g]; bz[g][1] = 0.f; bz[g][2] = 0.f; bz[g][3] = 0.f; }

    // ---------------- zero LDS (initial h states, x pad, PROG) ----------------
    {
        int* xz = (int*)XL;
        for (int i = tid; i < 2 * 32 * 256; i += NTH) xz[i] = 0;
        int* hz = (int*)HT;
        for (int i = tid; i < 3 * 4 * 512; i += NTH) hz[i] = 0;
        if (tid < 12) PROG[tid] = 0;
    }
    __syncthreads();

    // ---------------- x staging: sample bl -> A-row 4*bl, frag layout ------------
    auto stage_x = [&](int chunk) {
        if (tid < 4 * 22) {
            const int bl = tid / 22, ii = tid - bl * 22;
            const float* src = x + (size_t)(b4 + bl) * (22 * 512) + (size_t)ii * 512
                                 + chunk * 32;
            h16* dst = &XL[(chunk & 1) * (32 * 512) + (ii >> 3) * 128 + (4 * bl) * 8 + (ii & 7)];
            #pragma unroll
            for (int q = 0; q < 8; ++q) {
                const float4 v = ((const float4*)src)[q];
                dst[(q * 4 + 0) * 512] = (h16)v.x;
                dst[(q * 4 + 1) * 512] = (h16)v.y;
                dst[(q * 4 + 2) * 512] = (h16)v.z;
                dst[(q * 4 + 3) * 512] = (h16)v.w;
            }
        }
    };
    stage_x(0);
    __syncthreads();

    // ---------------- per-lane constants ----------------
    const int lo8  = lane * 8;                           // A-frag offset (h16 units)
    const int hoff = (u >> 3) * 128 + kg * 32 + (u & 7); // h-write: row 4*kg, unit u
    h16* const HT0 = HT;
    h16* const HT1 = HT + 4096;
    h16* const HT2 = HT + 8192;

    float cst = 0.f;

    auto ew = [&](const f32x4& zi, const f32x4& zf, const f32x4& zg, const f32x4& zo,
                  h16* hb) {
        const float vi = sigm(zi[0]);
        const float vf = sigm(zf[0]);
        const float vg = 2.f * sigm(2.f * zg[0]) - 1.f;
        const float vo = sigm(zo[0]);
        const float c  = vf * cst + vi * vg;
        cst = c;
        hb[hoff] = (h16)(vo * (2.f * sigm(2.f * c) - 1.f));
    };

    // spin until min(PROG[4g..4g+3]) >= need (monotone counters; skip if need<=0)
    auto waitge = [&](int grp, int need) {
        if (need <= 0) return;
        volatile unsigned* p = (volatile unsigned*)&PROG[4 * grp];
        for (;;) {
            unsigned a = p[0], b = p[1], c = p[2], d = p[3];
            unsigned m = a < b ? a : b;
            unsigned n = c < d ? c : d;
            m = m < n ? m : n;
            if ((int)m >= need) return;
            __builtin_amdgcn_s_sleep(1);
        }
    };
    auto publish = [&](int val) {
        __threadfence_block();                 // drain h ds_writes before flag
        if (lane == 0) ((volatile unsigned*)PROG)[w] = (unsigned)val;
    };

    // ============================ barrier-free loops ============================
    if (wl == 0) {                 // ---------------- L0 ----------------
        #pragma unroll 1
        for (int t = 0; t < TT; ++t) {
            waitge(0, t);          // h0(t-1) fully written by own group
            waitge(1, t - 3);      // ring back-pressure: L1 consumed h0(t-4)
            __threadfence_block(); // acquire
            const h16* hs = HT0 + ((t - 1) & 3) * 1024;
            const h16x8 ax   = *(const h16x8*)&XL[((t >> 5) & 1) * (32 * 512)
                                                  + (t & 31) * 512 + lo8];
            const h16x8 aSlo = *(const h16x8*)(hs + lo8);
            const h16x8 aShi = *(const h16x8*)(hs + lo8 + 512);
            f32x4 z[4];
            #pragma unroll
            for (int g = 0; g < 4; ++g) {
                z[g] = MFMA16(ax,   Bf[g][0], bz[g]);
                z[g] = MFMA16(aSlo, Bf[g][1], z[g]);
                z[g] = MFMA16(aShi, Bf[g][2], z[g]);
            }
            ew(z[0], z[1], z[2], z[3], HT0 + (t & 3) * 1024);
            publish(t + 1);
            if ((t & 31) == 16 && (t >> 5) < 15) stage_x((t >> 5) + 1);
        }
    } else if (wl == 1) {          // ---------------- L1 ----------------
        #pragma unroll 1
        for (int t = 0; t < TT; ++t) {
            waitge(0, t + 1);      // h0(t) ready (cross, same timestep)
            waitge(1, t);          // h1(t-1) own group
            waitge(2, t - 3);      // ring back-pressure: L2 consumed h1(t-4)
            __threadfence_block();
            const h16* hc = HT0 + (t & 3) * 1024;
            const h16* hs = HT1 + ((t - 1) & 3) * 1024;
            const h16x8 aClo = *(const h16x8*)(hc + lo8);
            const h16x8 aChi = *(const h16x8*)(hc + lo8 + 512);
            const h16x8 aSlo = *(const h16x8*)(hs + lo8);
            const h16x8 aShi = *(const h16x8*)(hs + lo8 + 512);
            f32x4 z[4];
            #pragma unroll
            for (int g = 0; g < 4; ++g) {
                z[g] = MFMA16(aClo, Bf[g][0], bz[g]);
                z[g] = MFMA16(aChi, Bf[g][1], z[g]);
                z[g] = MFMA16(aSlo, Bf[g][2], z[g]);
                z[g] = MFMA16(aShi, Bf[g][3], z[g]);
            }
            ew(z[0], z[1], z[2], z[3], HT1 + (t & 3) * 1024);
            publish(t + 1);
        }
    } else {                       // ---------------- L2 ----------------
        #pragma unroll 1
        for (int t = 0; t < TT; ++t) {
            waitge(1, t + 1);      // h1(t) ready (cross)
            waitge(2, t);          // h2(t-1) own group
            __threadfence_block();
            const h16* hc = HT1 + (t & 3) * 1024;
            const h16* hs = HT2 + ((t - 1) & 3) * 1024;
            const h16x8 aClo = *(const h16x8*)(hc + lo8);
            const h16x8 aChi = *(const h16x8*)(hc + lo8 + 512);
            const h16x8 aSlo = *(const h16x8*)(hs + lo8);
            const h16x8 aShi = *(const h16x8*)(hs + lo8 + 512);
            f32x4 z[4];
            #pragma unroll
            for (int g = 0; g < 4; ++g) {
                z[g] = MFMA16(aClo, Bf[g][0], bz[g]);
                z[g] = MFMA16(aChi, Bf[g][1], z[g]);
                z[g] = MFMA16(aSlo, Bf[g][2], z[g]);
                z[g] = MFMA16(aShi, Bf[g][3], z[g]);
            }
            ew(z[0], z[1], z[2], z[3], HT2 + (t & 3) * 1024);
            publish(t + 1);
        }
    }

    // ---------- FC epilogue: wait for L2 complete, h2(511) in slot 3 ----------
    if (tid < 16) {
        volatile unsigned* p = (volatile unsigned*)&PROG[8];
        for (;;) {
            unsigned a = p[0], b = p[1], c = p[2], d = p[3];
            unsigned m = a < b ? a : b;
            unsigned n = c < d ? c : d;
            m = m < n ? m : n;
            if (m >= (unsigned)TT) break;
            __builtin_amdgcn_s_sleep(1);
        }
        __threadfence_block();
        const int ms = tid >> 2, o = tid & 3;
        const h16* h2 = HT2 + ((TT - 1) & 3) * 1024;
        float acc = bfc[o];
        #pragma unroll 1
        for (int uu = 0; uu < 64; ++uu)
            acc += (float)h2[(uu >> 3) * 128 + (4 * ms) * 8 + (uu & 7)] * wfc[o * 64 + uu];
        out[(b4 + ms) * 4 + o] = acc;
    }
}

extern "C" void kernel_launch(void* const* d_in, const int* in_sizes, int n_in,
                              void* d_out, int out_size, void* d_ws, size_t ws_size,
                              hipStream_t stream) {
    const float* x    = (const float*)d_in[0];
    const float* wih0 = (const float*)d_in[1];
    const float* whh0 = (const float*)d_in[2];
    const float* bih0 = (const float*)d_in[3];
    const float* bhh0 = (const float*)d_in[4];
    const float* wih1 = (const float*)d_in[5];
    const float* whh1 = (const float*)d_in[6];
    const float* bih1 = (const float*)d_in[7];
    const float* bhh1 = (const float*)d_in[8];
    const float* wih2 = (const float*)d_in[9];
    const float* whh2 = (const float*)d_in[10];
    const float* bih2 = (const float*)d_in[11];
    const float* bhh2 = (const float*)d_in[12];
    const float* wfc  = (const float*)d_in[13];
    const float* bfc  = (const float*)d_in[14];
    float* out = (float*)d_out;

    lstm_mfma<<<dim3(NBLK), dim3(NTH), 0, stream>>>(
        x, wih0, whh0, bih0, bhh0, wih1, whh1, bih1, bhh1,
        wih2, whh2, bih2, bhh2, wfc, bfc, out);
}

// Round 11
// 422.225 us; speedup vs baseline: 1.2104x; 1.2104x over previous
//
#include <hip/hip_runtime.h>

// LSTM_61203283968689 — R11 (= R10 + s_setprio const fix): R6 barrier structure
// + per-layer static wave priority stagger.
// 256 blocks x 768 threads (12 waves, 3/SIMD): waves 0-3 L0(t), 4-7 L1(t-1),
// 8-11 L2(t-2). ONE barrier per tick (R6 = best so far, 370 us steady).
// R9 showed dataflow sync re-phase-locks (sum of pipes, not max). Floor math:
// 176 MFMA/block/tick x 19.4 cy/SIMD = ~854 cy/SIMD/tick mandatory matrix exec
// (~182 us). R6's loss: all 3 waves/SIMD burst MFMA together then ew together.
// R11: static wave priority L0=3, L1=2, L2=1 (constant-imm s_setprio per branch)
// -> arbitration drains waves' MFMA bursts sequentially; early finishers run
// latency-bound ew under later waves' MFMA bursts -> matrix pipe stays fed.
// Wave wg owns gates {i,f,g,o} of units [16wg,16wg+16); 4 samples on C-rows
// {0,4,8,12}. Fragment-linear LDS; lane reads at lane*16B (conflict-free).

#define TT   512
#define NTH  768
#define NBLK 256

typedef _Float16 h16;
typedef __attribute__((ext_vector_type(8))) _Float16 h16x8;
typedef __attribute__((ext_vector_type(4))) float f32x4;

#define MFMA16(a, b, c) __builtin_amdgcn_mfma_f32_16x16x32_f16((a), (b), (c), 0, 0, 0)

__device__ __forceinline__ float sigm(float z) {
    return __builtin_amdgcn_rcpf(1.f + __expf(-z));
}

// B-fragment: 8 consecutive k of row `ro` from row-major W[.,ld], f32 -> f16.
__device__ __forceinline__ h16x8 loadB(const float* __restrict__ W, int ld, int ro,
                                       int k0, int kmax) {
    h16x8 r;
    #pragma unroll
    for (int i = 0; i < 8; ++i) {
        const int k = k0 + i;
        r[i] = (h16)((k < kmax) ? W[(size_t)ro * ld + k] : 0.f);
    }
    return r;
}

__global__ __attribute__((amdgpu_flat_work_group_size(NTH, NTH), amdgpu_waves_per_eu(3)))
void lstm_mfma(
    const float* __restrict__ x,
    const float* __restrict__ wih0, const float* __restrict__ whh0,
    const float* __restrict__ bih0, const float* __restrict__ bhh0,
    const float* __restrict__ wih1, const float* __restrict__ whh1,
    const float* __restrict__ bih1, const float* __restrict__ bhh1,
    const float* __restrict__ wih2, const float* __restrict__ whh2,
    const float* __restrict__ bih2, const float* __restrict__ bhh2,
    const float* __restrict__ wfc, const float* __restrict__ bfc,
    float* __restrict__ out)
{
    const int tid  = threadIdx.x;
    const int w    = tid >> 6;        // wave 0..11
    const int wl   = w >> 2;          // layer 0..2
    const int wg   = w & 3;           // gate-tile group: units [16wg, 16wg+16)
    const int lane = tid & 63;
    const int nloc = lane & 15;       // unit-local index / B-frag col
    const int kg   = lane >> 4;       // k-group 0..3 ; also sample (C-row 4*kg)
    const int b4   = blockIdx.x * 4;
    const int u    = wg * 16 + nloc;  // this lane's hidden unit

    // stagger: L0 wave drains the matrix pipe first, L1 next, L2 last.
    // (s_setprio imm must be a literal constant -> uniform branch)
    if (wl == 0)      __builtin_amdgcn_s_setprio(3);
    else if (wl == 1) __builtin_amdgcn_s_setprio(2);
    else              __builtin_amdgcn_s_setprio(1);

    // LDS: XL 64 KiB + HT 12 KiB + PAD 6 KiB = 82 KiB -> 1 block/CU
    __shared__ alignas(16) h16 XL[2 * 32 * 512];   // x: 2 chunk-bufs x 32 t x frag(512)
    __shared__ alignas(16) h16 HT[3 * 2 * 1024];   // h[layer][pp] frag-tiles
    __shared__ h16 PAD[3072];                      // occupancy limiter (kept alive below)

    // ---------------- B fragments for THIS wave's layer only ----------------
    // L0: {x(wih0), h0lo(whh0), h0hi(whh0)}  L1: {h0lo,h0hi(wih1), h1lo,h1hi(whh1)}
    // L2: {h1lo,h1hi(wih2), h2lo,h2hi(whh2)}
    h16x8 Bf[4][4];
    float bias[4];
    #pragma unroll
    for (int g = 0; g < 4; ++g) {
        const int ro = g * 64 + u;                  // original row (i,f,g,o blocks)
        if (wl == 0) {
            Bf[g][0] = loadB(wih0, 22, ro, kg * 8,      22);
            Bf[g][1] = loadB(whh0, 64, ro, kg * 8,      64);
            Bf[g][2] = loadB(whh0, 64, ro, 32 + kg * 8, 64);
            Bf[g][3] = Bf[g][2];
            bias[g]  = bih0[ro] + bhh0[ro];
        } else if (wl == 1) {
            Bf[g][0] = loadB(wih1, 64, ro, kg * 8,      64);
            Bf[g][1] = loadB(wih1, 64, ro, 32 + kg * 8, 64);
            Bf[g][2] = loadB(whh1, 64, ro, kg * 8,      64);
            Bf[g][3] = loadB(whh1, 64, ro, 32 + kg * 8, 64);
            bias[g]  = bih1[ro] + bhh1[ro];
        } else {
            Bf[g][0] = loadB(wih2, 64, ro, kg * 8,      64);
            Bf[g][1] = loadB(wih2, 64, ro, 32 + kg * 8, 64);
            Bf[g][2] = loadB(whh2, 64, ro, kg * 8,      64);
            Bf[g][3] = loadB(whh2, 64, ro, 32 + kg * 8, 64);
            bias[g]  = bih2[ro] + bhh2[ro];
        }
    }

    // keep PAD alive (condition can never be true at runtime)
    if (bias[0] > 1.0e30f) { PAD[tid & 2047] = (h16)bias[0]; out[0] = (float)PAD[0]; }

    // ---------------- zero LDS (pad rows must stay zero) ----------------
    {
        int* xz = (int*)XL;
        for (int i = tid; i < 2 * 32 * 256; i += NTH) xz[i] = 0;
        int* hz = (int*)HT;
        for (int i = tid; i < 3 * 2 * 512; i += NTH) hz[i] = 0;
    }
    __syncthreads();

    // ---------------- x staging: sample bl -> A-row 4*bl, frag layout ------------
    // frag element (m, k) at (k>>3)*128 + m*8 + (k&7) within a 512-slab per t.
    auto stage_x = [&](int chunk) {
        if (tid < 4 * 22) {
            const int bl = tid / 22, ii = tid - bl * 22;
            const float* src = x + (size_t)(b4 + bl) * (22 * 512) + (size_t)ii * 512
                                 + chunk * 32;
            h16* dst = &XL[(chunk & 1) * (32 * 512) + (ii >> 3) * 128 + (4 * bl) * 8 + (ii & 7)];
            #pragma unroll
            for (int q = 0; q < 8; ++q) {
                const float4 v = ((const float4*)src)[q];
                dst[(q * 4 + 0) * 512] = (h16)v.x;
                dst[(q * 4 + 1) * 512] = (h16)v.y;
                dst[(q * 4 + 2) * 512] = (h16)v.z;
                dst[(q * 4 + 3) * 512] = (h16)v.w;
            }
        }
    };
    stage_x(0);

    // ---------------- per-lane constants ----------------
    const int lo8  = lane * 8;                           // A-frag offset (h16 units)
    const int hoff = (u >> 3) * 128 + kg * 32 + (u & 7); // h-write: row 4*kg, unit u

    float cst = 0.f;

    // elementwise: 4 gates in-lane, update c, emit h. 10 trans per call.
    auto ew = [&](const f32x4& zi, const f32x4& zf, const f32x4& zg, const f32x4& zo,
                  h16* hb) {
        const float vi = sigm(zi[0]);
        const float vf = sigm(zf[0]);
        const float vg = 2.f * sigm(2.f * zg[0]) - 1.f;
        const float vo = sigm(zo[0]);
        const float c  = vf * cst + vi * vg;
        cst = c;
        hb[hoff] = (h16)(vo * (2.f * sigm(2.f * c) - 1.f));
    };

    __syncthreads();

    // ============================ diagonal tick loop ============================
    #pragma unroll 1
    for (int t = 0; t < TT + 2; ++t) {
        const int wb = t & 1, rb = wb ^ 1;
        const h16* h0r = HT + 0 * 2048 + rb * 1024;
        h16*       h0w = HT + 0 * 2048 + wb * 1024;
        const h16* h1r = HT + 1 * 2048 + rb * 1024;
        h16*       h1w = HT + 1 * 2048 + wb * 1024;
        const h16* h2r = HT + 2 * 2048 + rb * 1024;
        h16*       h2w = HT + 2 * 2048 + wb * 1024;

        if (wl == 0) {           // -------- L0 (time t): x(t), h0(t-1) --------
            if (t < TT) {
                const h16x8 ax   = *(const h16x8*)&XL[((t >> 5) & 1) * (32 * 512)
                                                      + (t & 31) * 512 + lo8];
                const h16x8 a0lo = *(const h16x8*)(h0r + lo8);
                const h16x8 a0hi = *(const h16x8*)(h0r + lo8 + 512);
                f32x4 z[4];
                #pragma unroll
                for (int g = 0; g < 4; ++g) {
                    z[g] = f32x4{bias[g], 0.f, 0.f, 0.f};
                    z[g] = MFMA16(ax,   Bf[g][0], z[g]);
                    z[g] = MFMA16(a0lo, Bf[g][1], z[g]);
                    z[g] = MFMA16(a0hi, Bf[g][2], z[g]);
                }
                ew(z[0], z[1], z[2], z[3], h0w);
            }
            // stage next x chunk mid-window (visible after this tick's barrier)
            if ((t & 31) == 16 && (t >> 5) < 15) stage_x((t >> 5) + 1);
        } else if (wl == 1) {    // ---- L1 (time t-1): h0(t-1), h1(t-2) ----
            if (t >= 1 && t < TT + 1) {
                const h16x8 a0lo = *(const h16x8*)(h0r + lo8);
                const h16x8 a0hi = *(const h16x8*)(h0r + lo8 + 512);
                const h16x8 a1lo = *(const h16x8*)(h1r + lo8);
                const h16x8 a1hi = *(const h16x8*)(h1r + lo8 + 512);
                f32x4 z[4];
                #pragma unroll
                for (int g = 0; g < 4; ++g) {
                    z[g] = f32x4{bias[g], 0.f, 0.f, 0.f};
                    z[g] = MFMA16(a0lo, Bf[g][0], z[g]);
                    z[g] = MFMA16(a0hi, Bf[g][1], z[g]);
                    z[g] = MFMA16(a1lo, Bf[g][2], z[g]);
                    z[g] = MFMA16(a1hi, Bf[g][3], z[g]);
                }
                ew(z[0], z[1], z[2], z[3], h1w);
            }
        } else {                 // ------ L2 (time t-2): h1(t-2), h2(t-3) ------
            if (t >= 2) {
                const h16x8 a1lo = *(const h16x8*)(h1r + lo8);
                const h16x8 a1hi = *(const h16x8*)(h1r + lo8 + 512);
                const h16x8 a2lo = *(const h16x8*)(h2r + lo8);
                const h16x8 a2hi = *(const h16x8*)(h2r + lo8 + 512);
                f32x4 z[4];
                #pragma unroll
                for (int g = 0; g < 4; ++g) {
                    z[g] = f32x4{bias[g], 0.f, 0.f, 0.f};
                    z[g] = MFMA16(a1lo, Bf[g][0], z[g]);
                    z[g] = MFMA16(a1hi, Bf[g][1], z[g]);
                    z[g] = MFMA16(a2lo, Bf[g][2], z[g]);
                    z[g] = MFMA16(a2hi, Bf[g][3], z[g]);
                }
                ew(z[0], z[1], z[2], z[3], h2w);
            }
        }

        __syncthreads();
    }

    // ------------- FC epilogue: h2(time 511) is in buffer (TT+1)&1 = 1 -----------
    if (tid < 16) {
        const int ms = tid >> 2, o = tid & 3;
        const h16* h2 = HT + 2 * 2048 + 1024;
        float acc = bfc[o];
        #pragma unroll 1
        for (int uu = 0; uu < 64; ++uu)
            acc += (float)h2[(uu >> 3) * 128 + (4 * ms) * 8 + (uu & 7)] * wfc[o * 64 + uu];
        out[(b4 + ms) * 4 + o] = acc;
    }
}

extern "C" void kernel_launch(void* const* d_in, const int* in_sizes, int n_in,
                              void* d_out, int out_size, void* d_ws, size_t ws_size,
                              hipStream_t stream) {
    const float* x    = (const float*)d_in[0];
    const float* wih0 = (const float*)d_in[1];
    const float* whh0 = (const float*)d_in[2];
    const float* bih0 = (const float*)d_in[3];
    const float* bhh0 = (const float*)d_in[4];
    const float* wih1 = (const float*)d_in[5];
    const float* whh1 = (const float*)d_in[6];
    const float* bih1 = (const float*)d_in[7];
    const float* bhh1 = (const float*)d_in[8];
    const float* wih2 = (const float*)d_in[9];
    const float* whh2 = (const float*)d_in[10];
    const float* bih2 = (const float*)d_in[11];
    const float* bhh2 = (const float*)d_in[12];
    const float* wfc  = (const float*)d_in[13];
    const float* bfc  = (const float*)d_in[14];
    float* out = (float*)d_out;

    lstm_mfma<<<dim3(NBLK), dim3(NTH), 0, stream>>>(
        x, wih0, whh0, bih0, bhh0, wih1, whh1, bih1, bhh1,
        wih2, whh2, bih2, bhh2, wfc, bfc, out);
}